// Round 11
// baseline (210.138 us; speedup 1.0000x reference)
//
#include <hip/hip_runtime.h>
#include <hip/hip_fp16.h>

// Problem constants: B=2, T=32, H=64, W=64, C=64, KT=5, K=7. Circular dims pow2 -> & masks.
// Intermediates are CHANNEL-MAJOR: uint array [pair=c/2][b][t][h][w], pair stride 262144 uints.
#define NELEM 16777216

typedef _Float16 f16x8 __attribute__((ext_vector_type(8)));
typedef _Float16 h2v  __attribute__((ext_vector_type(2)));
typedef float f32x4 __attribute__((ext_vector_type(4)));

// packed f16 fma, tap in SGPR (VOP3P allows 1 SGPR source)
static __device__ __forceinline__ void pk_fma_sv(uint& d, uint a_s, uint b_v) {
    asm("v_pk_fma_f16 %0, %1, %2, %0" : "+v"(d) : "s"(a_s), "v"(b_v));
}

// ---------------- fused dual projection GEMM (MFMA f16, channel-major out) ----------------
__global__ __launch_bounds__(256) void proj2_kernel(
    const float* __restrict__ x,
    const float* __restrict__ wg, const float* __restrict__ bg,
    const float* __restrict__ wh, const float* __restrict__ bh,
    uint* __restrict__ pg, uint* __restrict__ ph)
{
    __shared__ __align__(16) _Float16 sX[128 * 64];
    __shared__ __align__(16) _Float16 sWT[2][64 * 64];
    const int tid = threadIdx.x;
    const int row0 = (int)blockIdx.x * 128;

    #pragma unroll
    for (int kci = 0; kci < 4; ++kci) {
        const int chunk = tid + kci * 256;
        const int r = chunk >> 3, q = chunk & 7;
        const float* gp = x + (long long)(row0 + r) * 64 + q * 8;
        const float4 v0 = *reinterpret_cast<const float4*>(gp);
        const float4 v1 = *reinterpret_cast<const float4*>(gp + 4);
        f16x8 hv;
        hv[0] = (_Float16)v0.x; hv[1] = (_Float16)v0.y; hv[2] = (_Float16)v0.z; hv[3] = (_Float16)v0.w;
        hv[4] = (_Float16)v1.x; hv[5] = (_Float16)v1.y; hv[6] = (_Float16)v1.z; hv[7] = (_Float16)v1.w;
        *reinterpret_cast<f16x8*>(&sX[r * 64 + ((q ^ (r & 7)) * 8)]) = hv;
    }
    {
        const int d = tid & 63;
        const int cb = (tid >> 6) * 16;
        #pragma unroll
        for (int i = 0; i < 16; ++i) {
            const int c = cb + i;
            const int off = d * 64 + (((c >> 3) ^ (d & 7)) * 8) + (c & 7);
            sWT[0][off] = (_Float16)wg[c * 64 + d];
            sWT[1][off] = (_Float16)wh[c * 64 + d];
        }
    }
    __syncthreads();

    const int wv = tid >> 6, lm = tid & 15, lg = (tid & 63) >> 4;
    f16x8 bf[2][4][2];
    #pragma unroll
    for (int nt = 0; nt < 4; ++nt) {
        const int d = nt * 16 + lm;
        #pragma unroll
        for (int s = 0; s < 2; ++s) {
            const int off = d * 64 + (((s * 4 + lg) ^ (d & 7)) * 8);
            bf[0][nt][s] = *reinterpret_cast<const f16x8*>(&sWT[0][off]);
            bf[1][nt][s] = *reinterpret_cast<const f16x8*>(&sWT[1][off]);
        }
    }
    f32x4 acc[2][2][4];
    #pragma unroll
    for (int m = 0; m < 2; ++m)
        #pragma unroll
        for (int mt = 0; mt < 2; ++mt)
            #pragma unroll
            for (int nt = 0; nt < 4; ++nt)
                acc[m][mt][nt] = (f32x4){0.f, 0.f, 0.f, 0.f};

    #pragma unroll
    for (int mt = 0; mt < 2; ++mt) {
        const int r = wv * 32 + mt * 16 + lm;
        const f16x8 a0 = *reinterpret_cast<const f16x8*>(&sX[r * 64 + ((lg ^ (r & 7)) * 8)]);
        const f16x8 a1 = *reinterpret_cast<const f16x8*>(&sX[r * 64 + (((4 + lg) ^ (r & 7)) * 8)]);
        #pragma unroll
        for (int nt = 0; nt < 4; ++nt) {
            acc[0][mt][nt] = __builtin_amdgcn_mfma_f32_16x16x32_f16(a0, bf[0][nt][0], acc[0][mt][nt], 0, 0, 0);
            acc[0][mt][nt] = __builtin_amdgcn_mfma_f32_16x16x32_f16(a1, bf[0][nt][1], acc[0][mt][nt], 0, 0, 0);
            acc[1][mt][nt] = __builtin_amdgcn_mfma_f32_16x16x32_f16(a0, bf[1][nt][0], acc[1][mt][nt], 0, 0, 0);
            acc[1][mt][nt] = __builtin_amdgcn_mfma_f32_16x16x32_f16(a1, bf[1][nt][1], acc[1][mt][nt], 0, 0, 0);
        }
    }
    // epilogue: pair lanes (lm, lm^1) via shfl, even lane stores uint4 (4 rows) channel-major
    #pragma unroll
    for (int nt = 0; nt < 4; ++nt) {
        const int col = nt * 16 + lm;
        const int pr  = col >> 1;
        const float bgv = bg[col], bhv = bh[col];
        #pragma unroll
        for (int mt = 0; mt < 2; ++mt) {
            const int rb = row0 + wv * 32 + mt * 16 + lg * 4;
            uint pk0[4], pk1[4];
            #pragma unroll
            for (int i = 0; i < 4; ++i) {
                const float v0 = acc[0][mt][nt][i] + bgv;
                const float p0 = __shfl_xor(v0, 1);
                const float v1 = acc[1][mt][nt][i] + bhv;
                const float p1 = __shfl_xor(v1, 1);
                h2v a, c;
                a[0] = (_Float16)((lm & 1) ? p0 : v0); a[1] = (_Float16)((lm & 1) ? v0 : p0);
                c[0] = (_Float16)((lm & 1) ? p1 : v1); c[1] = (_Float16)((lm & 1) ? v1 : p1);
                pk0[i] = __builtin_bit_cast(uint, a);
                pk1[i] = __builtin_bit_cast(uint, c);
            }
            if (!(lm & 1)) {
                *reinterpret_cast<uint4*>(pg + pr * 262144 + rb) = make_uint4(pk0[0], pk0[1], pk0[2], pk0[3]);
                *reinterpret_cast<uint4*>(ph + pr * 262144 + rb) = make_uint4(pk1[0], pk1[1], pk1[2], pk1[3]);
            }
        }
    }
}

// ---------------- tap pre-convert: f32 kernels -> packed f16 pair table ----------------
// taps[((mat*32 + p)*35 + kt*7+kh)*8 + kw], kw=7 zero-padded
__global__ __launch_bounds__(256) void tapconv_kernel(
    const float* __restrict__ gk, const float* __restrict__ hk, uint* __restrict__ taps)
{
    const int i = blockIdx.x * 256 + threadIdx.x;   // [0, 17920)
    if (i >= 17920) return;
    const int kw = i & 7;
    int r = i >> 3;
    const int kth = r % 35;  r /= 35;
    const int p = r & 31;
    const int mat = r >> 5;
    if (kw >= 7) { taps[i] = 0u; return; }
    const float* K = mat ? hk : gk;
    const int tap = kth * 7 + kw;
    h2v hv;
    hv[0] = (_Float16)K[(2 * p) * 245 + tap];
    hv[1] = (_Float16)K[(2 * p + 1) * 245 + tap];
    taps[i] = __builtin_bit_cast(uint, hv);
}

// ---------------- depthwise circular 3D conv: LDS-FREE, pipelined, channel-major ----------------
// Wave = one channel-pair over one 32x32 tile; lane (iy,ix) computes 4h x 4w.
// Rows read directly from global (SGPR plane base + hoisted voffsets), double-buffered
// (rowA/rowB) so rr+1's loads hide under rr's FMAs. Taps in SGPRs (uniform s_loads).
// FMA order (kw,o,j): same-accumulator reuse distance 16. No LDS, no barriers.
__global__ __launch_bounds__(256) void conv3d_dual_kernel(
    const uint* __restrict__ inG, uint* __restrict__ outG,
    const uint* __restrict__ inH, uint* __restrict__ outH,
    const uint* __restrict__ taps)
{
    const int bid = (int)blockIdx.x;                // 0..4095
    const int l = ((bid & 7) << 9) | (bid >> 3);    // chunked XCD swizzle (r9/r10-proven)
    const int tile = l & 3;
    const int pgrp = (l >> 2) & 7;
    const int t    = (l >> 5) & 31;
    const int b    = (l >> 10) & 1;
    const int mat  = (l >> 11) & 1;
    const int wave = threadIdx.x >> 6;
    const int lane = threadIdx.x & 63;
    const int h0 = (tile >> 1) * 32, w0 = (tile & 1) * 32;
    const int pair = pgrp * 4 + wave;

    const uint* in = mat ? inH : inG;
    uint* out      = mat ? outH : outG;

    const int iy = lane >> 3, ix = lane & 7;

    // wave-uniform SGPR bases
    const int tapOff = __builtin_amdgcn_readfirstlane((mat * 32 + pair) * 280);
    const uint* tb = taps + tapOff;
    const int pbOff = __builtin_amdgcn_readfirstlane(pair * 262144 + b * 131072);

    // hoisted per-lane offsets (kt-invariant)
    int colu[3];
    #pragma unroll
    for (int m = 0; m < 3; ++m) colu[m] = (w0 + 4 * ix - 4 + 4 * m) & 63;
    int rowu[10];
    #pragma unroll
    for (int rr = 0; rr < 10; ++rr) rowu[rr] = ((h0 - 3 + 4 * iy + rr) & 63) * 64;

    uint tot[4][4];
    #pragma unroll
    for (int o = 0; o < 4; ++o)
        #pragma unroll
        for (int j = 0; j < 4; ++j) tot[o][j] = 0u;

    #pragma unroll 1
    for (int kt = 0; kt < 5; ++kt) {
        const int tin = (t - kt + 2) & 31;
        const uint* pin = in + pbOff + tin * 4096;      // SGPR base
        const uint* tkt = tb + kt * 56;

        uint kv[7][8];                                  // SGPR tap block (uniform loads)
        #pragma unroll
        for (int kh = 0; kh < 7; ++kh)
            #pragma unroll
            for (int i2 = 0; i2 < 8; ++i2) kv[kh][i2] = tkt[kh * 8 + i2];

        uint rowA[12], rowB[12];
        // prologue: load rr=0 rows
        #pragma unroll
        for (int m = 0; m < 3; ++m) {
            const uint4 v = *reinterpret_cast<const uint4*>(pin + rowu[0] + colu[m]);
            rowA[4 * m] = v.x; rowA[4 * m + 1] = v.y; rowA[4 * m + 2] = v.z; rowA[4 * m + 3] = v.w;
        }

        #pragma unroll
        for (int rr = 0; rr < 10; ++rr) {
            uint* cur = (rr & 1) ? rowB : rowA;         // static after unroll
            uint* nxt = (rr & 1) ? rowA : rowB;
            if (rr < 9) {                               // issue next row's loads first
                #pragma unroll
                for (int m = 0; m < 3; ++m) {
                    const uint4 v = *reinterpret_cast<const uint4*>(pin + rowu[rr + 1] + colu[m]);
                    nxt[4 * m] = v.x; nxt[4 * m + 1] = v.y; nxt[4 * m + 2] = v.z; nxt[4 * m + 3] = v.w;
                }
            }
            #pragma unroll
            for (int kw = 0; kw < 7; ++kw)
                #pragma unroll
                for (int o = 0; o < 4; ++o) {
                    const int kh = o + 6 - rr;
                    if (kh < 0 || kh > 6) continue;
                    #pragma unroll
                    for (int j = 0; j < 4; ++j)
                        pk_fma_sv(tot[o][j], kv[kh][kw], cur[j + 7 - kw]);
                }
        }
    }

    uint* ob = out + pair * 262144 + (b * 32 + t) * 4096;
    #pragma unroll
    for (int o = 0; o < 4; ++o)
        *reinterpret_cast<uint4*>(ob + (h0 + 4 * iy + o) * 64 + (w0 + 4 * ix)) =
            make_uint4(tot[o][0], tot[o][1], tot[o][2], tot[o][3]);
}

// ---------------- minGRU scan over T (f32 math, channel-major h2 I/O) ----------------
__global__ __launch_bounds__(256) void scan_kernel(
    const uint* __restrict__ gs, const uint* __restrict__ hs, uint* __restrict__ hout)
{
    const int tid = blockIdx.x * 256 + threadIdx.x;    // 0..262143
    const int base = (tid >> 12) * 131072 + (tid & 4095);
    float h0 = 0.f, h1 = 0.f;
    for (int t = 0; t < 32; ++t) {
        const int a = base + t * 4096;
        const float2 g  = __half22float2(__builtin_bit_cast(__half2, gs[a]));
        const float2 hv = __half22float2(__builtin_bit_cast(__half2, hs[a]));
        const float z0 = 1.f / (1.f + __expf(-g.x));
        const float z1 = 1.f / (1.f + __expf(-g.y));
        h0 = fmaf(1.f - z0, h0, z0 * fmaf(hv.x, hv.x, 1e-6f));
        h1 = fmaf(1.f - z1, h1, z1 * fmaf(hv.y, hv.y, 1e-6f));
        hout[a] = __builtin_bit_cast(uint, __floats2half2_rn(h0, h1));
    }
}

// ---------------- output GEMM (MFMA f16, channel-major in, f32 row-major out) ----------------
__global__ __launch_bounds__(256) void outgemm_kernel(
    const uint* __restrict__ hin, const float* __restrict__ w,
    const float* __restrict__ bias, float* __restrict__ out)
{
    __shared__ __align__(16) uint sXu[128 * 36];        // rows x 32 pairs (stride 36: 16B-aligned)
    __shared__ __align__(16) _Float16 sWT[64 * 64];
    const int tid = threadIdx.x;
    const int row0 = (int)blockIdx.x * 128;

    {   // stage 128 rows x 32 pairs from channel-major
        const int pr = tid >> 3, k = tid & 7;
        const uint* src = hin + pr * 262144 + row0 + k * 16;
        #pragma unroll
        for (int q = 0; q < 4; ++q) {
            const uint4 v = *reinterpret_cast<const uint4*>(src + q * 4);
            sXu[(k * 16 + q * 4 + 0) * 36 + pr] = v.x;
            sXu[(k * 16 + q * 4 + 1) * 36 + pr] = v.y;
            sXu[(k * 16 + q * 4 + 2) * 36 + pr] = v.z;
            sXu[(k * 16 + q * 4 + 3) * 36 + pr] = v.w;
        }
    }
    {
        const int d = tid & 63;
        const int cb = (tid >> 6) * 16;
        #pragma unroll
        for (int i = 0; i < 16; ++i) {
            const int c = cb + i;
            sWT[d * 64 + (((c >> 3) ^ (d & 7)) * 8) + (c & 7)] = (_Float16)w[c * 64 + d];
        }
    }
    __syncthreads();

    const int wv = tid >> 6, lm = tid & 15, lg = (tid & 63) >> 4;
    f16x8 bf[4][2];
    #pragma unroll
    for (int nt = 0; nt < 4; ++nt) {
        const int d = nt * 16 + lm;
        #pragma unroll
        for (int s = 0; s < 2; ++s)
            bf[nt][s] = *reinterpret_cast<const f16x8*>(&sWT[d * 64 + (((s * 4 + lg) ^ (d & 7)) * 8)]);
    }
    f32x4 acc[2][4];
    #pragma unroll
    for (int mt = 0; mt < 2; ++mt)
        #pragma unroll
        for (int nt = 0; nt < 4; ++nt)
            acc[mt][nt] = (f32x4){0.f, 0.f, 0.f, 0.f};

    #pragma unroll
    for (int mt = 0; mt < 2; ++mt) {
        const int r = wv * 32 + mt * 16 + lm;
        const f16x8 a0 = *reinterpret_cast<const f16x8*>(&sXu[r * 36 + lg * 4]);
        const f16x8 a1 = *reinterpret_cast<const f16x8*>(&sXu[r * 36 + 16 + lg * 4]);
        #pragma unroll
        for (int nt = 0; nt < 4; ++nt) {
            acc[mt][nt] = __builtin_amdgcn_mfma_f32_16x16x32_f16(a0, bf[nt][0], acc[mt][nt], 0, 0, 0);
            acc[mt][nt] = __builtin_amdgcn_mfma_f32_16x16x32_f16(a1, bf[nt][1], acc[mt][nt], 0, 0, 0);
        }
    }
    #pragma unroll
    for (int nt = 0; nt < 4; ++nt) {
        const int col = nt * 16 + lm;
        const float bv = bias[col];
        #pragma unroll
        for (int mt = 0; mt < 2; ++mt) {
            const long long rb = row0 + wv * 32 + mt * 16 + lg * 4;
            #pragma unroll
            for (int i = 0; i < 4; ++i)
                out[(rb + i) * 64 + col] = acc[mt][nt][i] + bv;
        }
    }
}

extern "C" void kernel_launch(void* const* d_in, const int* in_sizes, int n_in,
                              void* d_out, int out_size, void* d_ws, size_t ws_size,
                              hipStream_t stream)
{
    const float* x  = (const float*)d_in[0];
    const float* gw = (const float*)d_in[1];
    const float* gb = (const float*)d_in[2];
    const float* hw = (const float*)d_in[3];
    const float* hb = (const float*)d_in[4];
    const float* gk = (const float*)d_in[5];
    const float* hk = (const float*)d_in[6];
    const float* ow = (const float*)d_in[7];
    const float* ob = (const float*)d_in[8];

    uint* W1 = (uint*)d_ws;                  // 33.5 MB each (channel-major h2)
    uint* W2 = W1 + NELEM / 2;
    uint* W3 = W2 + NELEM / 2;
    uint* taps = W3 + NELEM / 2;             // 71.7 KB tap table
    uint* Dsc = (uint*)d_out;                // hidden_spatial scratch (first 33.5MB of d_out)

    // 0) tap table
    tapconv_kernel<<<70, 256, 0, stream>>>(gk, hk, taps);
    // 1) proj: x -> W1 (gate_proj cm), W2 (hidden_proj cm)
    proj2_kernel<<<2048, 256, 0, stream>>>(x, gw, gb, hw, hb, W1, W2);
    // 2+3) dual conv (LDS-free, pipelined): W1 -> W3 (gate_sp), W2 -> Dsc (hidden_sp)
    conv3d_dual_kernel<<<4096, 256, 0, stream>>>(W1, W3, W2, Dsc, taps);
    // 4) scan: (W3, Dsc) -> W1 (h, cm)
    scan_kernel<<<1024, 256, 0, stream>>>(W3, Dsc, W1);
    // 5) out GEMM: W1 -> d_out (f32 row-major, overwrites scratch)
    outgemm_kernel<<<2048, 256, 0, stream>>>(W1, ow, ob, (float*)d_out);
}